// Round 1
// baseline (273.067 us; speedup 1.0000x reference)
//
#include <hip/hip_runtime.h>

typedef unsigned short ushort_t;
typedef unsigned int uint_t;
typedef __attribute__((ext_vector_type(8))) __bf16 bf16x8;
typedef __attribute__((ext_vector_type(4))) float f32x4;

#define NN 4096
#define BB 4
#define DD 4
#define TT 5
#define F1 32
#define F2 64
#define COLS 256  // BB*F2

// round-to-nearest-even fp32 -> bf16 bits
__device__ __forceinline__ ushort_t f2bf(float x) {
    union { float f; uint_t u; } v; v.f = x;
    uint_t r = (v.u + 0x7FFFu + ((v.u >> 16) & 1u)) >> 16;
    return (ushort_t)r;
}
// fp32 -> bf16 -> fp32 (same rounding as f2bf)
__device__ __forceinline__ float bf16f(float x) {
    union { float f; uint_t u; } v; v.f = x;
    v.u = (v.u + 0x7FFFu + ((v.u >> 16) & 1u)) & 0xFFFF0000u;
    return v.f;
}

// ---------------- K1: temporal convs -> cond (fp32 [b][j][f]) + condT (bf16 [col][j]) ----
__global__ __launch_bounds__(256) void k1_cond(
    const float* __restrict__ ts, const float* __restrict__ Wc1, const float* __restrict__ bc1,
    const float* __restrict__ Wc2, const float* __restrict__ bc2,
    float* __restrict__ condf, ushort_t* __restrict__ condT)
{
    const int b = blockIdx.y;
    const int j0 = blockIdx.x * 64;
    const int t = threadIdx.x;

    __shared__ float sWc1[384];
    __shared__ float sbc1[F1];
    __shared__ float sWc2[96 * F2];
    __shared__ float sbc2[F2];
    __shared__ float sh1[4][96];
    __shared__ ushort_t scb[64][66];   // [f2][node], padded

    for (int i = t; i < 384; i += 256) sWc1[i] = Wc1[i];
    for (int i = t; i < 96 * F2; i += 256) sWc2[i] = Wc2[i];
    if (t < F1) sbc1[t] = bc1[t];
    if (t < F2) sbc2[t] = bc2[t];
    __syncthreads();

    const int sub = t >> 6, lane = t & 63;
    for (int c = 0; c < 16; ++c) {
        const int n = c * 4 + sub;
        const int j = j0 + n;
        // phase A: h1[3][32]
        for (int idx = lane; idx < 96; idx += 64) {
            const int tt0 = idx >> 5, f1 = idx & 31;
            float a = sbc1[f1];
            #pragma unroll
            for (int dt = 0; dt < 3; ++dt) {
                const float4 x = *(const float4*)(ts + (((b * TT + tt0 + dt) * NN) + j) * DD);
                a += x.x * sWc1[(dt * 4 + 0) * F1 + f1];
                a += x.y * sWc1[(dt * 4 + 1) * F1 + f1];
                a += x.z * sWc1[(dt * 4 + 2) * F1 + f1];
                a += x.w * sWc1[(dt * 4 + 3) * F1 + f1];
            }
            sh1[sub][idx] = fmaxf(a, 0.f);
        }
        __syncthreads();
        // phase B: cond[f2]
        {
            float cacc = sbc2[lane];
            #pragma unroll 8
            for (int e = 0; e < 96; ++e) cacc += sh1[sub][e] * sWc2[e * F2 + lane];
            condf[(((b << 12) + j) << 6) + lane] = cacc;
            scb[lane][n] = f2bf(cacc);
        }
        __syncthreads();
    }
    // writeback condT tile (64 f2 x 64 j), 32B per thread
    {
        const int f2 = t >> 2, seg = t & 3;
        const ushort_t* src = &scb[f2][seg * 16];
        uint_t u[8];
        #pragma unroll
        for (int q = 0; q < 8; ++q)
            u[q] = (uint_t)src[2 * q] | ((uint_t)src[2 * q + 1] << 16);
        ushort_t* dst = condT + ((b * 64 + f2) * NN) + j0 + seg * 16;
        *(uint4*)(dst) = make_uint4(u[0], u[1], u[2], u[3]);
        *(uint4*)(dst + 8) = make_uint4(u[4], u[5], u[6], u[7]);
    }
}

// ---------------- K2: row degrees + column-alive bits ------------------------------------
__global__ __launch_bounds__(256) void k2_deg(
    const int* __restrict__ edges, float* __restrict__ deg, uint_t* __restrict__ colbits)
{
    const int t = threadIdx.x;
    const int r0 = blockIdx.x * 16;
    __shared__ uint_t lbits[128];
    __shared__ float wsum[4][16];
    if (t < 128) lbits[t] = 0u;
    __syncthreads();

    uint_t nib[4] = {0u, 0u, 0u, 0u};
    for (int jr = 0; jr < 16; ++jr) {
        const int j = r0 + jr;
        int s = 0;
        #pragma unroll
        for (int ci = 0; ci < 4; ++ci) {
            const int4 v = *(const int4*)(edges + (size_t)j * NN + ci * 1024 + t * 4);
            s += v.x + v.y + v.z + v.w;
            uint_t m = (uint_t)(v.x != 0) | ((uint_t)(v.y != 0) << 1) |
                       ((uint_t)(v.z != 0) << 2) | ((uint_t)(v.w != 0) << 3);
            nib[ci] |= m;
        }
        #pragma unroll
        for (int off = 32; off >= 1; off >>= 1) s += __shfl_down(s, off, 64);
        if ((t & 63) == 0) wsum[t >> 6][jr] = (float)s;
    }
    #pragma unroll
    for (int ci = 0; ci < 4; ++ci)
        atomicOr(&lbits[ci * 32 + (t >> 3)], nib[ci] << ((t & 7) * 4));
    __syncthreads();
    if (t < 128) atomicOr(&colbits[t], lbits[t]);
    if (t < 16) deg[r0 + t] = wsum[0][t] + wsum[1][t] + wsum[2][t] + wsum[3][t];
}

// ---------------- K3: agg_raw[b][j][f] = sum_k edges[j][k] * bf16(cond[b][k][f]) ---------
// block = 512 thr (8 waves), tile: 16 j rows x 256 cols, BK=32, mfma 16x16x32_bf16
__global__ __launch_bounds__(512) void k3_gemm(
    const int* __restrict__ edges, const ushort_t* __restrict__ condT, float* __restrict__ agg)
{
    const int t = threadIdx.x;
    const int j0 = blockIdx.x * 16;
    __shared__ ushort_t sA[16 * 40];   // [j][k], stride 40
    __shared__ ushort_t sB[COLS * 40]; // [col][k], stride 40

    const int w = t >> 6, l = t & 63;
    const int cw0 = w * 32;
    f32x4 acc0 = {0.f, 0.f, 0.f, 0.f};
    f32x4 acc1 = {0.f, 0.f, 0.f, 0.f};

    const int bcol = t >> 1, bseg = t & 1;   // B staging: 2x16B per thread
    const int arow = t >> 3, aseg = t & 7;   // A staging: t<128, one int4

    uint4 pb0, pb1; int4 pa;
    // prefetch step 0
    {
        const ushort_t* bp = condT + (size_t)bcol * NN + bseg * 8;
        pb0 = *(const uint4*)(bp);
        pb1 = *(const uint4*)(bp + 16);
        if (t < 128) pa = *(const int4*)(edges + (size_t)(j0 + arow) * NN + aseg * 4);
    }

    for (int s = 0; s < 128; ++s) {
        __syncthreads();   // previous compute done; safe to overwrite LDS
        *(uint4*)&sB[bcol * 40 + bseg * 8] = pb0;
        *(uint4*)&sB[bcol * 40 + bseg * 8 + 16] = pb1;
        if (t < 128) {
            const uint_t lo = (pa.x ? 0x3F80u : 0u) | ((pa.y ? 0x3F80u : 0u) << 16);
            const uint_t hi = (pa.z ? 0x3F80u : 0u) | ((pa.w ? 0x3F80u : 0u) << 16);
            *(uint2*)&sA[arow * 40 + aseg * 4] = make_uint2(lo, hi);
        }
        __syncthreads();
        if (s < 127) {
            const int k0 = (s + 1) * 32;
            const ushort_t* bp = condT + (size_t)bcol * NN + k0 + bseg * 8;
            pb0 = *(const uint4*)(bp);
            pb1 = *(const uint4*)(bp + 16);
            if (t < 128) pa = *(const int4*)(edges + (size_t)(j0 + arow) * NN + k0 + aseg * 4);
        }
        const bf16x8 af  = *(const bf16x8*)&sA[(l & 15) * 40 + (l >> 4) * 8];
        const bf16x8 bf0 = *(const bf16x8*)&sB[(cw0 + (l & 15)) * 40 + (l >> 4) * 8];
        const bf16x8 bf1 = *(const bf16x8*)&sB[(cw0 + 16 + (l & 15)) * 40 + (l >> 4) * 8];
        acc0 = __builtin_amdgcn_mfma_f32_16x16x32_bf16(af, bf0, acc0, 0, 0, 0);
        acc1 = __builtin_amdgcn_mfma_f32_16x16x32_bf16(af, bf1, acc1, 0, 0, 0);
    }
    // epilogue: D[row=j_local][col], row=(l>>4)*4+i, col=l&15 within tile
    #pragma unroll
    for (int i = 0; i < 4; ++i) {
        const int j = j0 + (l >> 4) * 4 + i;
        const int col0 = cw0 + (l & 15);
        const int col1 = col0 + 16;
        agg[(((col0 >> 6) * NN + j) << 6) + (col0 & 63)] = acc0[i];
        agg[(((col1 >> 6) * NN + j) << 6) + (col1 & 63)] = acc1[i];
    }
}

// ---------------- K4: epilogue MLP per node ----------------------------------------------
__global__ __launch_bounds__(256) void k4_mlp(
    const float* __restrict__ ts, const int* __restrict__ edges,
    const float* __restrict__ condf, const float* __restrict__ aggraw,
    const float* __restrict__ deg, const uint_t* __restrict__ colbits,
    const float* __restrict__ Wg1, const float* __restrict__ bg,
    const float* __restrict__ Wd, const float* __restrict__ bd,
    const float* __restrict__ Wo, const float* __restrict__ bo,
    float* __restrict__ out)
{
    const int b = blockIdx.y;
    const int j0 = blockIdx.x * 64;
    const int t = threadIdx.x;

    __shared__ float sWg1[64 * 64];
    __shared__ float sWd[128 * 64];
    __shared__ float sWo[64 * 4];
    __shared__ float sbg[64], sbd[64], sbo[4];
    __shared__ float sAggT[64][68];
    __shared__ float sCatT[128][68];
    __shared__ float sH[64][68];
    __shared__ float sAlive[64];

    for (int i = t; i < 64 * 64; i += 256) sWg1[i] = Wg1[i];
    for (int i = t; i < 128 * 64; i += 256) sWd[i] = Wd[i];
    if (t < 256) sWo[t] = Wo[t];
    if (t < 64) { sbg[t] = bg[t]; sbd[t] = bd[t]; }
    if (t < 4) sbo[t] = bo[t];
    if (t < 64) {
        const int j = j0 + t;
        sAlive[t] = (float)((colbits[j >> 5] >> (j & 31)) & 1u);
    }
    // phase 0: corrected agg + cond into transposed LDS
    {
        const int n = t >> 2, fg = t & 3;
        const int j = j0 + n;
        const int dgv = edges[(size_t)j * NN + j];
        const float dv = deg[j];
        const float inv = 1.f / (dv > 0.f ? dv : 1.f);
        const float dgf = (float)dgv;
        const float* ap = aggraw + (((b << 12) + j) << 6) + fg * 16;
        const float* cp = condf + (((b << 12) + j) << 6) + fg * 16;
        #pragma unroll
        for (int i = 0; i < 4; ++i) {
            const float4 a4 = *(const float4*)(ap + i * 4);
            const float4 c4 = *(const float4*)(cp + i * 4);
            const int f = fg * 16 + i * 4;
            sAggT[f + 0][n] = (a4.x - dgf * bf16f(c4.x)) * inv;  sCatT[f + 0][n] = c4.x;
            sAggT[f + 1][n] = (a4.y - dgf * bf16f(c4.y)) * inv;  sCatT[f + 1][n] = c4.y;
            sAggT[f + 2][n] = (a4.z - dgf * bf16f(c4.z)) * inv;  sCatT[f + 2][n] = c4.z;
            sAggT[f + 3][n] = (a4.w - dgf * bf16f(c4.w)) * inv;  sCatT[f + 3][n] = c4.w;
        }
    }
    __syncthreads();
    // phase G: G = tanh(agg @ Wg1 + bg) * alive -> sCatT[64..127]
    {
        const int fq = t >> 4, nq = t & 15;
        const int g0 = fq << 2, n0 = nq << 2;
        float acc[4][4];
        #pragma unroll
        for (int gi = 0; gi < 4; ++gi)
            #pragma unroll
            for (int ni = 0; ni < 4; ++ni) acc[gi][ni] = sbg[g0 + gi];
        for (int e = 0; e < 64; ++e) {
            const float4 wv = *(const float4*)&sWg1[(e << 6) + g0];
            const float4 av = *(const float4*)&sAggT[e][n0];
            const float ww[4] = {wv.x, wv.y, wv.z, wv.w};
            const float aa[4] = {av.x, av.y, av.z, av.w};
            #pragma unroll
            for (int gi = 0; gi < 4; ++gi)
                #pragma unroll
                for (int ni = 0; ni < 4; ++ni) acc[gi][ni] += ww[gi] * aa[ni];
        }
        #pragma unroll
        for (int gi = 0; gi < 4; ++gi)
            #pragma unroll
            for (int ni = 0; ni < 4; ++ni)
                sCatT[64 + g0 + gi][n0 + ni] = tanhf(acc[gi][ni]) * sAlive[n0 + ni];
    }
    __syncthreads();
    // phase H: h = relu(cat @ Wd + bd) -> sH
    {
        const int fq = t >> 4, nq = t & 15;
        const int o0 = fq << 2, n0 = nq << 2;
        float acc[4][4];
        #pragma unroll
        for (int oi = 0; oi < 4; ++oi)
            #pragma unroll
            for (int ni = 0; ni < 4; ++ni) acc[oi][ni] = sbd[o0 + oi];
        for (int e = 0; e < 128; ++e) {
            const float4 wv = *(const float4*)&sWd[(e << 6) + o0];
            const float4 av = *(const float4*)&sCatT[e][n0];
            const float ww[4] = {wv.x, wv.y, wv.z, wv.w};
            const float aa[4] = {av.x, av.y, av.z, av.w};
            #pragma unroll
            for (int oi = 0; oi < 4; ++oi)
                #pragma unroll
                for (int ni = 0; ni < 4; ++ni) acc[oi][ni] += ww[oi] * aa[ni];
        }
        #pragma unroll
        for (int oi = 0; oi < 4; ++oi)
            #pragma unroll
            for (int ni = 0; ni < 4; ++ni)
                sH[o0 + oi][n0 + ni] = fmaxf(acc[oi][ni], 0.f);
    }
    __syncthreads();
    // phase O: out = seg_last + tanh(h @ Wo + bo)
    {
        const int d = t >> 6, n = t & 63;
        const int j = j0 + n;
        float s = sbo[d];
        #pragma unroll 8
        for (int f = 0; f < 64; ++f) s += sH[f][n] * sWo[f * 4 + d];
        const float segl = ts[(((b * TT + 4) * NN) + j) * DD + d];
        out[(((b << 12) + j) << 2) + d] = segl + tanhf(s);
    }
}

// ---------------- launcher ----------------------------------------------------------------
extern "C" void kernel_launch(void* const* d_in, const int* in_sizes, int n_in,
                              void* d_out, int out_size, void* d_ws, size_t ws_size,
                              hipStream_t stream)
{
    (void)in_sizes; (void)n_in; (void)out_size; (void)ws_size;
    const float* ts    = (const float*)d_in[0];
    const int*   edges = (const int*)d_in[1];
    const float* Wc1   = (const float*)d_in[2];
    const float* bc1   = (const float*)d_in[3];
    const float* Wc2   = (const float*)d_in[4];
    const float* bc2   = (const float*)d_in[5];
    const float* Wg1   = (const float*)d_in[6];
    const float* bg    = (const float*)d_in[7];
    const float* Wd    = (const float*)d_in[8];
    const float* bd    = (const float*)d_in[9];
    const float* Wo    = (const float*)d_in[10];
    const float* bo    = (const float*)d_in[11];
    float* out = (float*)d_out;

    char* ws = (char*)d_ws;
    ushort_t* condT  = (ushort_t*)(ws);                         // 2 MiB
    float*    condf  = (float*)(ws + (size_t)(2 << 20));        // 4 MiB
    float*    agg    = (float*)(ws + (size_t)(6 << 20));        // 4 MiB
    float*    deg    = (float*)(ws + (size_t)(10 << 20));       // 16 KiB
    uint_t*   colbits = (uint_t*)(ws + (size_t)(10 << 20) + 16384); // 512 B

    hipMemsetAsync(colbits, 0, 128 * sizeof(uint_t), stream);

    k1_cond<<<dim3(64, 4), 256, 0, stream>>>(ts, Wc1, bc1, Wc2, bc2, condf, condT);
    k2_deg<<<256, 256, 0, stream>>>(edges, deg, colbits);
    k3_gemm<<<256, 512, 0, stream>>>(edges, condT, agg);
    k4_mlp<<<dim3(64, 4), 256, 0, stream>>>(ts, edges, condf, agg, deg, colbits,
                                            Wg1, bg, Wd, bd, Wo, bo, out);
}

// Round 2
// 237.485 us; speedup vs baseline: 1.1498x; 1.1498x over previous
//
#include <hip/hip_runtime.h>

typedef unsigned short ushort_t;
typedef unsigned int uint_t;
typedef unsigned long long u64_t;
typedef __attribute__((ext_vector_type(8))) __bf16 bf16x8;
typedef __attribute__((ext_vector_type(4))) float f32x4;

#define NN 4096
#define TT 5
#define F1 32
#define F2 64

// round-to-nearest-even fp32 -> bf16 bits
__device__ __forceinline__ ushort_t f2bf(float x) {
    union { float f; uint_t u; } v; v.f = x;
    uint_t r = (v.u + 0x7FFFu + ((v.u >> 16) & 1u)) >> 16;
    return (ushort_t)r;
}
__device__ __forceinline__ float bf16f(float x) {
    union { float f; uint_t u; } v; v.f = x;
    v.u = (v.u + 0x7FFFu + ((v.u >> 16) & 1u)) & 0xFFFF0000u;
    return v.f;
}

// ---------------- K0: pack edges -> bits, deg (popcount), colbits (column OR) ------------
// grid 512 x 256thr; block = 8 rows, 2 rows per wave
__global__ __launch_bounds__(256) void k0_pack(
    const int* __restrict__ edges, uint_t* __restrict__ packed,
    float* __restrict__ deg, uint_t* __restrict__ colbits)
{
    const int t = threadIdx.x;
    const int r0 = blockIdx.x * 8;
    const int wv = t >> 6, lane = t & 63;
    const int ra = r0 + wv * 2, rb = ra + 1;
    __shared__ uint_t lbits[128];
    __shared__ uint_t spack[8][128];
    if (t < 128) lbits[t] = 0u;
    __syncthreads();

    int dega = 0, degb = 0;
    const int* pa = edges + (size_t)ra * NN + lane;
    const int* pb = edges + (size_t)rb * NN + lane;
    #pragma unroll 4
    for (int s = 0; s < 64; ++s) {
        const int e0 = pa[s * 64];
        const int e1 = pb[s * 64];
        const u64_t b0 = __ballot(e0 != 0);
        const u64_t b1 = __ballot(e1 != 0);
        dega += (int)__popcll(b0);
        degb += (int)__popcll(b1);
        const u64_t orr = b0 | b1;
        if (lane < 2)      spack[wv * 2][s * 2 + lane]           = (uint_t)(b0 >> (lane * 32));
        else if (lane < 4) spack[wv * 2 + 1][s * 2 + (lane - 2)] = (uint_t)(b1 >> ((lane - 2) * 32));
        else if (lane < 6) atomicOr(&lbits[s * 2 + (lane - 4)], (uint_t)(orr >> ((lane - 4) * 32)));
    }
    if (lane == 0) { deg[ra] = (float)dega; deg[rb] = (float)degb; }
    __syncthreads();
    {   // packed writeback: 8 rows x 512B, coalesced
        const uint_t* flat = &spack[0][0];
        *(uint4*)(packed + (size_t)r0 * 128 + t * 4) = *(const uint4*)(flat + t * 4);
    }
    if (t < 128) atomicOr(&colbits[t], lbits[t]);
}

// ---------------- K1: temporal convs -> condf (fp32 [b][j][f]) + condT (bf16 [col][j]) ---
// grid (128,4) x 256thr; 32 nodes/block
__global__ __launch_bounds__(256) void k1_cond(
    const float* __restrict__ ts, const float* __restrict__ Wc1, const float* __restrict__ bc1,
    const float* __restrict__ Wc2, const float* __restrict__ bc2,
    float* __restrict__ condf, ushort_t* __restrict__ condT)
{
    const int b = blockIdx.y;
    const int j0 = blockIdx.x * 32;
    const int t = threadIdx.x;

    __shared__ float sWc1[384];
    __shared__ float sbc1[F1];
    __shared__ float sWc2[96 * F2];
    __shared__ float sbc2[F2];
    __shared__ float sh1[4][96];
    __shared__ ushort_t scb[64][40];   // [f2][node], padded to 40 for aligned uint4 readback

    for (int i = t; i < 384; i += 256) sWc1[i] = Wc1[i];
    for (int i = t; i < 96 * F2; i += 256) sWc2[i] = Wc2[i];
    if (t < F1) sbc1[t] = bc1[t];
    if (t < F2) sbc2[t] = bc2[t];
    __syncthreads();

    const int sub = t >> 6, lane = t & 63;
    for (int c = 0; c < 8; ++c) {
        const int n = c * 4 + sub;
        const int j = j0 + n;
        for (int idx = lane; idx < 96; idx += 64) {
            const int tt0 = idx >> 5, f1 = idx & 31;
            float a = sbc1[f1];
            #pragma unroll
            for (int dt = 0; dt < 3; ++dt) {
                const float4 x = *(const float4*)(ts + (((b * TT + tt0 + dt) * NN) + j) * 4);
                a += x.x * sWc1[(dt * 4 + 0) * F1 + f1];
                a += x.y * sWc1[(dt * 4 + 1) * F1 + f1];
                a += x.z * sWc1[(dt * 4 + 2) * F1 + f1];
                a += x.w * sWc1[(dt * 4 + 3) * F1 + f1];
            }
            sh1[sub][idx] = fmaxf(a, 0.f);
        }
        __syncthreads();
        {
            float cacc = sbc2[lane];
            #pragma unroll 8
            for (int e = 0; e < 96; ++e) cacc += sh1[sub][e] * sWc2[e * F2 + lane];
            condf[(((b << 12) + j) << 6) + lane] = cacc;
            scb[lane][n] = f2bf(cacc);
        }
        __syncthreads();
    }
    {   // condT tile writeback: 64 f2 x 32 nodes, 16B/thread
        const int f2 = t >> 2, seg = t & 3;
        ushort_t* dst = condT + ((size_t)(b * 64 + f2) * NN) + j0 + seg * 8;
        *(uint4*)dst = *(const uint4*)&scb[f2][seg * 8];
    }
}

// ---------------- K3: agg_raw = bits(A) @ bf16(cond), barrier-free K-loop ----------------
// grid 512 = 128 row-tiles x 4 k-splits; 512thr (8 waves); tile 32r x 256c, K=1024/block
#define AST 1032   // abuf stride in halfs (pad 8)
__global__ __launch_bounds__(512) void k3_gemm(
    const uint_t* __restrict__ packed, const ushort_t* __restrict__ condT,
    float* __restrict__ agg)
{
    const int t = threadIdx.x;
    const int j0 = (blockIdx.x >> 2) * 32;
    const int kbase = (blockIdx.x & 3) * 1024;
    __shared__ ushort_t abuf[32 * AST];

    {   // stage 1: expand 32 rows x 1024 bits -> bf16 0/1 in LDS (once per block)
        const int row = t & 31;
        const int w0 = (t >> 5) * 2;
        const uint2 bits = *(const uint2*)(packed + (size_t)(j0 + row) * 128 + (kbase >> 5) + w0);
        uint_t* dst = (uint_t*)(abuf + row * AST);
        #pragma unroll
        for (int h = 0; h < 2; ++h) {
            const uint_t wb = h ? bits.y : bits.x;
            uint_t ex[16];
            #pragma unroll
            for (int p = 0; p < 16; ++p)
                ex[p] = (((wb >> (2 * p)) & 1u) ? 0x3F80u : 0u)
                      | (((wb >> (2 * p + 1)) & 1u) ? 0x3F800000u : 0u);
            uint_t* d2 = dst + (w0 + h) * 16;
            *(uint4*)(d2 + 0)  = make_uint4(ex[0], ex[1], ex[2], ex[3]);
            *(uint4*)(d2 + 4)  = make_uint4(ex[4], ex[5], ex[6], ex[7]);
            *(uint4*)(d2 + 8)  = make_uint4(ex[8], ex[9], ex[10], ex[11]);
            *(uint4*)(d2 + 12) = make_uint4(ex[12], ex[13], ex[14], ex[15]);
        }
    }
    __syncthreads();

    const int wv = t >> 6, l = t & 63;
    const int c0 = wv * 32;
    f32x4 acc[2][2] = {};
    const ushort_t* a0p = abuf + (l & 15) * AST + (l >> 4) * 8;
    const ushort_t* a1p = a0p + 16 * AST;
    const ushort_t* b0p = condT + (size_t)(c0 + (l & 15)) * NN + kbase + (l >> 4) * 8;
    const ushort_t* b1p = b0p + (size_t)16 * NN;

    #pragma unroll 4
    for (int kk = 0; kk < 32; ++kk) {
        const bf16x8 a0 = *(const bf16x8*)(a0p + kk * 32);
        const bf16x8 a1 = *(const bf16x8*)(a1p + kk * 32);
        const bf16x8 b0 = *(const bf16x8*)(b0p + kk * 32);
        const bf16x8 b1 = *(const bf16x8*)(b1p + kk * 32);
        acc[0][0] = __builtin_amdgcn_mfma_f32_16x16x32_bf16(a0, b0, acc[0][0], 0, 0, 0);
        acc[0][1] = __builtin_amdgcn_mfma_f32_16x16x32_bf16(a0, b1, acc[0][1], 0, 0, 0);
        acc[1][0] = __builtin_amdgcn_mfma_f32_16x16x32_bf16(a1, b0, acc[1][0], 0, 0, 0);
        acc[1][1] = __builtin_amdgcn_mfma_f32_16x16x32_bf16(a1, b1, acc[1][1], 0, 0, 0);
    }
    #pragma unroll
    for (int rt = 0; rt < 2; ++rt)
        #pragma unroll
        for (int ct = 0; ct < 2; ++ct)
            #pragma unroll
            for (int i = 0; i < 4; ++i) {
                const int j = j0 + rt * 16 + (l >> 4) * 4 + i;
                const int col = c0 + ct * 16 + (l & 15);
                unsafeAtomicAdd(&agg[(((size_t)(col >> 6) * NN + j) << 6) + (col & 63)],
                                acc[rt][ct][i]);
            }
}

// ---------------- K4: epilogue MLP, 32 nodes/block, grid (128,4) -------------------------
__global__ __launch_bounds__(256) void k4_mlp(
    const float* __restrict__ ts, const uint_t* __restrict__ packed,
    const float* __restrict__ condf, const float* __restrict__ aggraw,
    const float* __restrict__ deg, const uint_t* __restrict__ colbits,
    const float* __restrict__ Wg1, const float* __restrict__ bg,
    const float* __restrict__ Wd, const float* __restrict__ bd,
    const float* __restrict__ Wo, const float* __restrict__ bo,
    float* __restrict__ out)
{
    const int b = blockIdx.y;
    const int j0 = blockIdx.x * 32;
    const int t = threadIdx.x;

    __shared__ float sWg1[64 * 64];
    __shared__ float sWd[128 * 64];
    __shared__ float sWo[256];
    __shared__ float sbg[64], sbd[64], sbo[4];
    __shared__ float sAggT[64][36];   // phase0/G input; reused as H output in phase H
    __shared__ float sCatT[128][36];
    __shared__ float sAlive[32];

    for (int i = t; i < 64 * 64; i += 256) sWg1[i] = Wg1[i];
    for (int i = t; i < 128 * 64; i += 256) sWd[i] = Wd[i];
    if (t < 256) sWo[t] = Wo[t];
    if (t < 64) { sbg[t] = bg[t]; sbd[t] = bd[t]; }
    if (t < 4) sbo[t] = bo[t];
    if (t < 32) {
        const int j = j0 + t;
        sAlive[t] = (float)((colbits[j >> 5] >> (j & 31)) & 1u);
    }
    {   // phase 0: corrected agg + cond into transposed LDS
        const int n = t >> 3, fg = t & 7;
        const int j = j0 + n;
        const uint_t dbit = (packed[(size_t)j * 128 + (j >> 5)] >> (j & 31)) & 1u;
        const float dv = deg[j];
        const float inv = 1.f / (dv > 0.f ? dv : 1.f);
        const float dgf = (float)dbit;
        const float* ap = aggraw + (((size_t)(b << 12) + j) << 6) + fg * 8;
        const float* cp = condf + (((size_t)(b << 12) + j) << 6) + fg * 8;
        #pragma unroll
        for (int i = 0; i < 2; ++i) {
            const float4 a4 = *(const float4*)(ap + i * 4);
            const float4 c4 = *(const float4*)(cp + i * 4);
            const int f = fg * 8 + i * 4;
            sAggT[f + 0][n] = (a4.x - dgf * bf16f(c4.x)) * inv;  sCatT[f + 0][n] = c4.x;
            sAggT[f + 1][n] = (a4.y - dgf * bf16f(c4.y)) * inv;  sCatT[f + 1][n] = c4.y;
            sAggT[f + 2][n] = (a4.z - dgf * bf16f(c4.z)) * inv;  sCatT[f + 2][n] = c4.z;
            sAggT[f + 3][n] = (a4.w - dgf * bf16f(c4.w)) * inv;  sCatT[f + 3][n] = c4.w;
        }
    }
    __syncthreads();
    {   // phase G: G = tanh(agg @ Wg1 + bg) * alive -> sCatT[64..127]; 2g x 4n per thread
        const int g0 = (t >> 3) * 2, n0 = (t & 7) * 4;
        float acc[2][4];
        #pragma unroll
        for (int gi = 0; gi < 2; ++gi)
            #pragma unroll
            for (int ni = 0; ni < 4; ++ni) acc[gi][ni] = sbg[g0 + gi];
        for (int e = 0; e < 64; ++e) {
            const float2 wv = *(const float2*)&sWg1[(e << 6) + g0];
            const float4 av = *(const float4*)&sAggT[e][n0];
            const float aa[4] = {av.x, av.y, av.z, av.w};
            #pragma unroll
            for (int ni = 0; ni < 4; ++ni) { acc[0][ni] += wv.x * aa[ni]; acc[1][ni] += wv.y * aa[ni]; }
        }
        #pragma unroll
        for (int gi = 0; gi < 2; ++gi)
            #pragma unroll
            for (int ni = 0; ni < 4; ++ni)
                sCatT[64 + g0 + gi][n0 + ni] = tanhf(acc[gi][ni]) * sAlive[n0 + ni];
    }
    __syncthreads();
    {   // phase H: h = relu(cat @ Wd + bd) -> sAggT (reuse); 2h x 4n per thread
        const int h0 = (t >> 3) * 2, n0 = (t & 7) * 4;
        float acc[2][4];
        #pragma unroll
        for (int hi = 0; hi < 2; ++hi)
            #pragma unroll
            for (int ni = 0; ni < 4; ++ni) acc[hi][ni] = sbd[h0 + hi];
        for (int e = 0; e < 128; ++e) {
            const float2 wv = *(const float2*)&sWd[(e << 6) + h0];
            const float4 av = *(const float4*)&sCatT[e][n0];
            const float aa[4] = {av.x, av.y, av.z, av.w};
            #pragma unroll
            for (int ni = 0; ni < 4; ++ni) { acc[0][ni] += wv.x * aa[ni]; acc[1][ni] += wv.y * aa[ni]; }
        }
        __syncthreads();
        #pragma unroll
        for (int hi = 0; hi < 2; ++hi)
            #pragma unroll
            for (int ni = 0; ni < 4; ++ni)
                sAggT[h0 + hi][n0 + ni] = fmaxf(acc[hi][ni], 0.f);
    }
    __syncthreads();
    if (t < 128) {   // phase O: out = seg_last + tanh(h @ Wo + bo)
        const int d = t >> 5, n = t & 31;
        const int j = j0 + n;
        float s = sbo[d];
        #pragma unroll 8
        for (int f = 0; f < 64; ++f) s += sAggT[f][n] * sWo[f * 4 + d];
        const float segl = ts[(((b * TT + 4) * NN) + j) * 4 + d];
        out[((((size_t)b << 12) + j) << 2) + d] = segl + tanhf(s);
    }
}

// ---------------- launcher ----------------------------------------------------------------
extern "C" void kernel_launch(void* const* d_in, const int* in_sizes, int n_in,
                              void* d_out, int out_size, void* d_ws, size_t ws_size,
                              hipStream_t stream)
{
    (void)in_sizes; (void)n_in; (void)out_size; (void)ws_size;
    const float* ts    = (const float*)d_in[0];
    const int*   edges = (const int*)d_in[1];
    const float* Wc1   = (const float*)d_in[2];
    const float* bc1   = (const float*)d_in[3];
    const float* Wc2   = (const float*)d_in[4];
    const float* bc2   = (const float*)d_in[5];
    const float* Wg1   = (const float*)d_in[6];
    const float* bg    = (const float*)d_in[7];
    const float* Wd    = (const float*)d_in[8];
    const float* bd    = (const float*)d_in[9];
    const float* Wo    = (const float*)d_in[10];
    const float* bo    = (const float*)d_in[11];
    float* out = (float*)d_out;

    char* ws = (char*)d_ws;
    ushort_t* condT   = (ushort_t*)(ws);                               // 2 MiB
    float*    condf   = (float*)(ws + (size_t)(2 << 20));              // 4 MiB
    float*    agg     = (float*)(ws + (size_t)(6 << 20));              // 4 MiB
    uint_t*   colbits = (uint_t*)(ws + (size_t)(10 << 20));            // 512 B
    float*    deg     = (float*)(ws + (size_t)(10 << 20) + 1024);      // 16 KiB
    uint_t*   packed  = (uint_t*)(ws + (size_t)(10 << 20) + 1024 + 16384); // 2 MiB

    // zero agg + colbits in one memset (colbits sits right after agg)
    hipMemsetAsync(agg, 0, (size_t)(4 << 20) + 512, stream);

    k0_pack<<<512, 256, 0, stream>>>(edges, packed, deg, colbits);
    k1_cond<<<dim3(128, 4), 256, 0, stream>>>(ts, Wc1, bc1, Wc2, bc2, condf, condT);
    k3_gemm<<<512, 512, 0, stream>>>(packed, condT, agg);
    k4_mlp<<<dim3(128, 4), 256, 0, stream>>>(ts, packed, condf, agg, deg, colbits,
                                             Wg1, bg, Wd, bd, Wo, bo, out);
}

// Round 3
// 200.064 us; speedup vs baseline: 1.3649x; 1.1870x over previous
//
#include <hip/hip_runtime.h>

typedef unsigned short ushort_t;
typedef unsigned int uint_t;
typedef unsigned long long u64_t;
typedef __attribute__((ext_vector_type(8))) __bf16 bf16x8;
typedef __attribute__((ext_vector_type(4))) float f32x4;

#define NN 4096
#define TT 5
#define F1 32
#define F2 64

// round-to-nearest-even fp32 -> bf16 bits
__device__ __forceinline__ ushort_t f2bf(float x) {
    union { float f; uint_t u; } v; v.f = x;
    uint_t r = (v.u + 0x7FFFu + ((v.u >> 16) & 1u)) >> 16;
    return (ushort_t)r;
}
__device__ __forceinline__ float bf16f(float x) {
    union { float f; uint_t u; } v; v.f = x;
    v.u = (v.u + 0x7FFFu + ((v.u >> 16) & 1u)) & 0xFFFF0000u;
    return v.f;
}

// ---------------- K1: temporal convs -> condf (fp32 [b][j][f]) + condT (bf16 [col][j]) ---
__global__ __launch_bounds__(256) void k1_cond(
    const float* __restrict__ ts, const float* __restrict__ Wc1, const float* __restrict__ bc1,
    const float* __restrict__ Wc2, const float* __restrict__ bc2,
    float* __restrict__ condf, ushort_t* __restrict__ condT)
{
    const int b = blockIdx.y;
    const int j0 = blockIdx.x * 32;
    const int t = threadIdx.x;

    __shared__ float sWc1[384];
    __shared__ float sbc1[F1];
    __shared__ float sWc2[96 * F2];
    __shared__ float sbc2[F2];
    __shared__ float sh1[4][96];
    __shared__ ushort_t scb[64][40];

    for (int i = t; i < 384; i += 256) sWc1[i] = Wc1[i];
    for (int i = t; i < 96 * F2; i += 256) sWc2[i] = Wc2[i];
    if (t < F1) sbc1[t] = bc1[t];
    if (t < F2) sbc2[t] = bc2[t];
    __syncthreads();

    const int sub = t >> 6, lane = t & 63;
    for (int c = 0; c < 8; ++c) {
        const int n = c * 4 + sub;
        const int j = j0 + n;
        for (int idx = lane; idx < 96; idx += 64) {
            const int tt0 = idx >> 5, f1 = idx & 31;
            float a = sbc1[f1];
            #pragma unroll
            for (int dt = 0; dt < 3; ++dt) {
                const float4 x = *(const float4*)(ts + (((b * TT + tt0 + dt) * NN) + j) * 4);
                a += x.x * sWc1[(dt * 4 + 0) * F1 + f1];
                a += x.y * sWc1[(dt * 4 + 1) * F1 + f1];
                a += x.z * sWc1[(dt * 4 + 2) * F1 + f1];
                a += x.w * sWc1[(dt * 4 + 3) * F1 + f1];
            }
            sh1[sub][idx] = fmaxf(a, 0.f);
        }
        __syncthreads();
        {
            float cacc = sbc2[lane];
            #pragma unroll 8
            for (int e = 0; e < 96; ++e) cacc += sh1[sub][e] * sWc2[e * F2 + lane];
            condf[(((b << 12) + j) << 6) + lane] = cacc;
            scb[lane][n] = f2bf(cacc);
        }
        __syncthreads();
    }
    {
        const int f2 = t >> 2, seg = t & 3;
        ushort_t* dst = condT + ((size_t)(b * 64 + f2) * NN) + j0 + seg * 8;
        *(uint4*)dst = *(const uint4*)&scb[f2][seg * 8];
    }
}

// ---------------- K3: fused edges->GEMM + deg + colbits ----------------------------------
// grid 256 = 128 row-stripes(32r) x 2 k-halves(2048); 1024 thr (16 waves)
// wave tile 32r x 16c; A double-buffered in LDS (fragment order, XOR swizzle);
// B direct b128 global loads from L2-resident condT. Plain stores to slab[kh].
__device__ __forceinline__ void stage_chunk(
    const int4 pa, int it, int kq, ushort_t* dstbuf, int soff, u64_t& regm, int& cnt)
{
    const u64_t b0 = __ballot(pa.x != 0);
    const u64_t b1 = __ballot(pa.y != 0);
    const u64_t b2 = __ballot(pa.z != 0);
    const u64_t b3 = __ballot(pa.w != 0);
    const uint_t m0 = (uint_t)(b0 | (b0 >> 32)), m1 = (uint_t)(b1 | (b1 >> 32));
    const uint_t m2 = (uint_t)(b2 | (b2 >> 32)), m3 = (uint_t)(b3 | (b3 >> 32));
    const uint_t nib = ((m0 >> kq) & 1u) | (((m1 >> kq) & 1u) << 1) |
                       (((m2 >> kq) & 1u) << 2) | (((m3 >> kq) & 1u) << 3);
    regm |= (u64_t)nib << (it * 4);
    cnt += (pa.x != 0) + (pa.y != 0) + (pa.z != 0) + (pa.w != 0);
    const uint_t h01 = (pa.x ? 0x3F80u : 0u) | (pa.y ? 0x3F800000u : 0u);
    const uint_t h23 = (pa.z ? 0x3F80u : 0u) | (pa.w ? 0x3F800000u : 0u);
    *(uint2*)(dstbuf + soff) = make_uint2(h01, h23);
}

__global__ __launch_bounds__(1024) void k3_gemm(
    const int* __restrict__ edges, const ushort_t* __restrict__ condT,
    float* __restrict__ agg0, float* __restrict__ agg1,
    int* __restrict__ degI, uint_t* __restrict__ colbits)
{
    const int t = threadIdx.x;
    const int stripe = blockIdx.x >> 1, kh = blockIdx.x & 1;
    const int j0 = stripe * 32, kb = kh * 2048;

    __shared__ __align__(16) ushort_t abuf[2][4096];  // 2 x 32r x 128k, frag order
    __shared__ int degs[1024];
    __shared__ u64_t colsh[16][32];
    __shared__ u64_t colr[32];

    const int w = t >> 6, l = t & 63;
    const int r = t >> 5, kq = t & 31;       // staging: row, int4-group (4 k each)
    const int rl = r & 15, rh = r >> 4;

    // staging LDS offset (halfs): element k = kq*4+c -> ks=kq>>3, q=(kq>>1)&3, j=(kq&1)*4+c
    const int ks_s = kq >> 3, q_s = (kq >> 1) & 3;
    const int soff = (rh * 2048 + ks_s * 512 + (q_s * 16 + rl) * 8 + (kq & 1) * 4) ^ (q_s << 4);
    // compute-side A frag offset (halfs) within a ks-section
    const int aoff = (l * 8) ^ ((l >> 4) << 4);

    const int* ep = edges + (size_t)(j0 + r) * NN + kb + kq * 4;
    const ushort_t* bp = condT + (size_t)(w * 16 + (l & 15)) * NN + kb + (l >> 4) * 8;

    u64_t regm = 0; int cnt = 0;
    int4 pa = *(const int4*)ep;
    stage_chunk(pa, 0, kq, &abuf[0][0], soff, regm, cnt);
    __syncthreads();

    f32x4 acc0 = {0.f, 0.f, 0.f, 0.f};
    f32x4 acc1 = {0.f, 0.f, 0.f, 0.f};

    for (int it = 0; it < 16; ++it) {
        if (it < 15) pa = *(const int4*)(ep + (it + 1) * 128);
        const ushort_t* ab = &abuf[it & 1][0];
        const ushort_t* bpi = bp + it * 128;
        #pragma unroll
        for (int ks = 0; ks < 4; ++ks) {
            const bf16x8 bfv = *(const bf16x8*)(bpi + ks * 32);
            const bf16x8 a0 = *(const bf16x8*)(ab + ks * 512 + aoff);
            const bf16x8 a1 = *(const bf16x8*)(ab + 2048 + ks * 512 + aoff);
            acc0 = __builtin_amdgcn_mfma_f32_16x16x32_bf16(a0, bfv, acc0, 0, 0, 0);
            acc1 = __builtin_amdgcn_mfma_f32_16x16x32_bf16(a1, bfv, acc1, 0, 0, 0);
        }
        if (it < 15) stage_chunk(pa, it + 1, kq, &abuf[(it + 1) & 1][0], soff, regm, cnt);
        __syncthreads();
    }

    // epilogue: plain stores to this k-half's slab
    {
        float* aggS = kh ? agg1 : agg0;
        const int col = w * 16 + (l & 15);
        float* dst = aggS + ((size_t)(col >> 6) * NN << 6) + (col & 63);
        #pragma unroll
        for (int i = 0; i < 4; ++i) {
            const int ja = j0 + (l >> 4) * 4 + i;
            dst[(size_t)ja << 6] = acc0[i];
            dst[(size_t)(ja + 16) << 6] = acc1[i];
        }
    }
    // deg + colbits reductions
    degs[t] = cnt;
    if (l < 32) colsh[w][kq] = regm;
    __syncthreads();
    if (t < 32) {
        u64_t v = 0;
        #pragma unroll
        for (int w2 = 0; w2 < 16; ++w2) v |= colsh[w2][t];
        colr[t] = v;
        int s = 0;
        #pragma unroll
        for (int s2 = 0; s2 < 32; ++s2) s += degs[t * 32 + s2];
        atomicAdd(&degI[j0 + t], s);
    }
    __syncthreads();
    if (t < 64) {
        uint_t word = 0;
        #pragma unroll
        for (int s = 0; s < 8; ++s) {
            const int g = (t & 3) * 8 + s;
            const uint_t nib = (uint_t)((colr[g] >> ((t >> 2) * 4)) & 15u);
            word |= nib << (s * 4);
        }
        atomicOr(&colbits[kh * 64 + t], word);
    }
}

// ---------------- K4: epilogue MLP, 32 nodes/block, grid (128,4) -------------------------
__global__ __launch_bounds__(256) void k4_mlp(
    const float* __restrict__ ts, const int* __restrict__ edges,
    const float* __restrict__ condf,
    const float* __restrict__ agg0, const float* __restrict__ agg1,
    const int* __restrict__ degI, const uint_t* __restrict__ colbits,
    const float* __restrict__ Wg1, const float* __restrict__ bg,
    const float* __restrict__ Wd, const float* __restrict__ bd,
    const float* __restrict__ Wo, const float* __restrict__ bo,
    float* __restrict__ out)
{
    const int b = blockIdx.y;
    const int j0 = blockIdx.x * 32;
    const int t = threadIdx.x;

    __shared__ float sWg1[64 * 64];
    __shared__ float sWd[128 * 64];
    __shared__ float sWo[256];
    __shared__ float sbg[64], sbd[64], sbo[4];
    __shared__ float sAggT[64][36];
    __shared__ float sCatT[128][36];
    __shared__ float sAlive[32];

    for (int i = t; i < 64 * 64; i += 256) sWg1[i] = Wg1[i];
    for (int i = t; i < 128 * 64; i += 256) sWd[i] = Wd[i];
    if (t < 256) sWo[t] = Wo[t];
    if (t < 64) { sbg[t] = bg[t]; sbd[t] = bd[t]; }
    if (t < 4) sbo[t] = bo[t];
    if (t < 32) {
        const int j = j0 + t;
        sAlive[t] = (float)((colbits[j >> 5] >> (j & 31)) & 1u);
    }
    {   // phase 0: corrected agg + cond into transposed LDS
        const int n = t >> 3, fg = t & 7;
        const int j = j0 + n;
        const int dbit = edges[(size_t)j * NN + j];
        const float dv = (float)degI[j];
        const float inv = 1.f / (dv > 0.f ? dv : 1.f);
        const float dgf = dbit ? 1.f : 0.f;
        const float* ap0 = agg0 + (((size_t)(b << 12) + j) << 6) + fg * 8;
        const float* ap1 = agg1 + (((size_t)(b << 12) + j) << 6) + fg * 8;
        const float* cp = condf + (((size_t)(b << 12) + j) << 6) + fg * 8;
        #pragma unroll
        for (int i = 0; i < 2; ++i) {
            const float4 a4 = *(const float4*)(ap0 + i * 4);
            const float4 b4 = *(const float4*)(ap1 + i * 4);
            const float4 c4 = *(const float4*)(cp + i * 4);
            const int f = fg * 8 + i * 4;
            sAggT[f + 0][n] = (a4.x + b4.x - dgf * bf16f(c4.x)) * inv;  sCatT[f + 0][n] = c4.x;
            sAggT[f + 1][n] = (a4.y + b4.y - dgf * bf16f(c4.y)) * inv;  sCatT[f + 1][n] = c4.y;
            sAggT[f + 2][n] = (a4.z + b4.z - dgf * bf16f(c4.z)) * inv;  sCatT[f + 2][n] = c4.z;
            sAggT[f + 3][n] = (a4.w + b4.w - dgf * bf16f(c4.w)) * inv;  sCatT[f + 3][n] = c4.w;
        }
    }
    __syncthreads();
    {   // phase G
        const int g0 = (t >> 3) * 2, n0 = (t & 7) * 4;
        float acc[2][4];
        #pragma unroll
        for (int gi = 0; gi < 2; ++gi)
            #pragma unroll
            for (int ni = 0; ni < 4; ++ni) acc[gi][ni] = sbg[g0 + gi];
        for (int e = 0; e < 64; ++e) {
            const float2 wv = *(const float2*)&sWg1[(e << 6) + g0];
            const float4 av = *(const float4*)&sAggT[e][n0];
            const float aa[4] = {av.x, av.y, av.z, av.w};
            #pragma unroll
            for (int ni = 0; ni < 4; ++ni) { acc[0][ni] += wv.x * aa[ni]; acc[1][ni] += wv.y * aa[ni]; }
        }
        #pragma unroll
        for (int gi = 0; gi < 2; ++gi)
            #pragma unroll
            for (int ni = 0; ni < 4; ++ni)
                sCatT[64 + g0 + gi][n0 + ni] = tanhf(acc[gi][ni]) * sAlive[n0 + ni];
    }
    __syncthreads();
    {   // phase H
        const int h0 = (t >> 3) * 2, n0 = (t & 7) * 4;
        float acc[2][4];
        #pragma unroll
        for (int hi = 0; hi < 2; ++hi)
            #pragma unroll
            for (int ni = 0; ni < 4; ++ni) acc[hi][ni] = sbd[h0 + hi];
        for (int e = 0; e < 128; ++e) {
            const float2 wv = *(const float2*)&sWd[(e << 6) + h0];
            const float4 av = *(const float4*)&sCatT[e][n0];
            const float aa[4] = {av.x, av.y, av.z, av.w};
            #pragma unroll
            for (int ni = 0; ni < 4; ++ni) { acc[0][ni] += wv.x * aa[ni]; acc[1][ni] += wv.y * aa[ni]; }
        }
        __syncthreads();
        #pragma unroll
        for (int hi = 0; hi < 2; ++hi)
            #pragma unroll
            for (int ni = 0; ni < 4; ++ni)
                sAggT[h0 + hi][n0 + ni] = fmaxf(acc[hi][ni], 0.f);
    }
    __syncthreads();
    if (t < 128) {   // phase O
        const int d = t >> 5, n = t & 31;
        const int j = j0 + n;
        float s = sbo[d];
        #pragma unroll 8
        for (int f = 0; f < 64; ++f) s += sAggT[f][n] * sWo[f * 4 + d];
        const float segl = ts[(((b * TT + 4) * NN) + j) * 4 + d];
        out[((((size_t)b << 12) + j) << 2) + d] = segl + tanhf(s);
    }
}

// ---------------- launcher ----------------------------------------------------------------
extern "C" void kernel_launch(void* const* d_in, const int* in_sizes, int n_in,
                              void* d_out, int out_size, void* d_ws, size_t ws_size,
                              hipStream_t stream)
{
    (void)in_sizes; (void)n_in; (void)out_size; (void)ws_size;
    const float* ts    = (const float*)d_in[0];
    const int*   edges = (const int*)d_in[1];
    const float* Wc1   = (const float*)d_in[2];
    const float* bc1   = (const float*)d_in[3];
    const float* Wc2   = (const float*)d_in[4];
    const float* bc2   = (const float*)d_in[5];
    const float* Wg1   = (const float*)d_in[6];
    const float* bg    = (const float*)d_in[7];
    const float* Wd    = (const float*)d_in[8];
    const float* bd    = (const float*)d_in[9];
    const float* Wo    = (const float*)d_in[10];
    const float* bo    = (const float*)d_in[11];
    float* out = (float*)d_out;

    char* ws = (char*)d_ws;
    ushort_t* condT   = (ushort_t*)(ws);                        // 2 MiB
    float*    condf   = (float*)(ws + (size_t)(2 << 20));       // 4 MiB
    float*    agg0    = (float*)(ws + (size_t)(6 << 20));       // 4 MiB
    float*    agg1    = (float*)(ws + (size_t)(10 << 20));      // 4 MiB
    int*      degI    = (int*)(ws + (size_t)(14 << 20));        // 16 KiB
    uint_t*   colbits = (uint_t*)(ws + (size_t)(14 << 20) + 16384); // 512 B

    hipMemsetAsync(degI, 0, 16384 + 512, stream);

    k1_cond<<<dim3(128, 4), 256, 0, stream>>>(ts, Wc1, bc1, Wc2, bc2, condf, condT);
    k3_gemm<<<256, 1024, 0, stream>>>(edges, condT, agg0, agg1, degI, colbits);
    k4_mlp<<<dim3(128, 4), 256, 0, stream>>>(ts, edges, condf, agg0, agg1, degI, colbits,
                                             Wg1, bg, Wd, bd, Wo, bo, out);
}

// Round 4
// 165.557 us; speedup vs baseline: 1.6494x; 1.2084x over previous
//
#include <hip/hip_runtime.h>
#include <math.h>

typedef unsigned short ushort_t;
typedef unsigned int uint_t;
typedef unsigned long long u64_t;
typedef __attribute__((ext_vector_type(8))) __bf16 bf16x8;
typedef __attribute__((ext_vector_type(4))) float f32x4;

#define NN 4096
#define TT 5
#define F1 32
#define F2 64

// round-to-nearest-even fp32 -> bf16 bits
__device__ __forceinline__ ushort_t f2bf(float x) {
    union { float f; uint_t u; } v; v.f = x;
    uint_t r = (v.u + 0x7FFFu + ((v.u >> 16) & 1u)) >> 16;
    return (ushort_t)r;
}
__device__ __forceinline__ float bf16f(float x) {
    union { float f; uint_t u; } v; v.f = x;
    v.u = (v.u + 0x7FFFu + ((v.u >> 16) & 1u)) & 0xFFFF0000u;
    return v.f;
}
__device__ __forceinline__ uint_t pk2(float a, float b) {
    return (uint_t)f2bf(a) | ((uint_t)f2bf(b) << 16);
}
// fast tanh: (e^2x - 1)/(e^2x + 1), clamped; err ~1e-6 (irrelevant vs bf16 noise)
__device__ __forceinline__ float tanh_fast(float x) {
    const float xc = fminf(fmaxf(x, -10.f), 10.f);
    const float e = __expf(2.f * xc);
    return (e - 1.f) * __builtin_amdgcn_rcpf(e + 1.f);
}

// ---------------- K1: conv1 (VALU) + conv2 (MFMA) -> condf fp32 + condT bf16 -------------
// grid (64,4) x 256thr; 64 nodes/block; 4 waves, each 16-node row-tile
#define H1S 104   // h1/Wc2T stride in halfs (208B: 16-aligned, 2-way banks)
#define CBS 80    // scb stride in halfs (160B: 16-aligned)
__global__ __launch_bounds__(256) void k1_cond(
    const float* __restrict__ ts, const float* __restrict__ Wc1, const float* __restrict__ bc1,
    const float* __restrict__ Wc2, const float* __restrict__ bc2,
    float* __restrict__ condf, ushort_t* __restrict__ condT)
{
    const int b = blockIdx.y;
    const int j0 = blockIdx.x * 64;
    const int t = threadIdx.x;

    __shared__ float sWc1[384];
    __shared__ float sbc1[F1];
    __shared__ float sbc2[F2];
    __shared__ ushort_t sWc2T[64 * H1S];   // [f2][e], bf16
    __shared__ ushort_t h1B[64 * H1S];     // [node][e], bf16
    __shared__ ushort_t scb[64 * CBS];     // [f2][node], bf16

    for (int i = t; i < 384; i += 256) sWc1[i] = Wc1[i];
    if (t < F1) sbc1[t] = bc1[t];
    if (t < F2) sbc2[t] = bc2[t];
    for (int i = t; i < 96 * 64; i += 256) {
        const int e = i >> 6, f = i & 63;
        sWc2T[f * H1S + e] = f2bf(Wc2[i]);
    }
    __syncthreads();

    // phase A: h1[node][e=tt0*32+f1] = relu(conv1), 24 values/thread (8 f1 x 3 tt0)
    {
        const int n = t & 63, f10 = (t >> 6) * 8;
        const int j = j0 + n;
        float4 x[5];
        #pragma unroll
        for (int tt = 0; tt < 5; ++tt)
            x[tt] = *(const float4*)(ts + ((((size_t)b * TT + tt) << 12) + j) * 4);
        #pragma unroll
        for (int tt0 = 0; tt0 < 3; ++tt0) {
            #pragma unroll
            for (int ff = 0; ff < 8; ++ff) {
                const int f1 = f10 + ff;
                float a = sbc1[f1];
                #pragma unroll
                for (int dt = 0; dt < 3; ++dt) {
                    const float4 xx = x[tt0 + dt];
                    a += xx.x * sWc1[(dt * 4 + 0) * F1 + f1];
                    a += xx.y * sWc1[(dt * 4 + 1) * F1 + f1];
                    a += xx.z * sWc1[(dt * 4 + 2) * F1 + f1];
                    a += xx.w * sWc1[(dt * 4 + 3) * F1 + f1];
                }
                h1B[n * H1S + tt0 * 32 + f1] = f2bf(fmaxf(a, 0.f));
            }
        }
    }
    __syncthreads();

    // phase B: cond = h1 @ Wc2 + bc2 via MFMA; wave w -> rows w*16..+15
    {
        const int w = t >> 6, l = t & 63;
        const int m0 = w * 16, kseg = (l >> 4) * 8;
        f32x4 acc[4] = {};
        #pragma unroll
        for (int ks = 0; ks < 3; ++ks) {
            const bf16x8 av = *(const bf16x8*)&h1B[(m0 + (l & 15)) * H1S + ks * 32 + kseg];
            #pragma unroll
            for (int ct = 0; ct < 4; ++ct) {
                const bf16x8 bv = *(const bf16x8*)&sWc2T[(ct * 16 + (l & 15)) * H1S + ks * 32 + kseg];
                acc[ct] = __builtin_amdgcn_mfma_f32_16x16x32_bf16(av, bv, acc[ct], 0, 0, 0);
            }
        }
        #pragma unroll
        for (int ct = 0; ct < 4; ++ct)
            #pragma unroll
            for (int i = 0; i < 4; ++i) {
                const int row = m0 + (l >> 4) * 4 + i;
                const int col = ct * 16 + (l & 15);
                const float c = acc[ct][i] + sbc2[col];
                condf[((((size_t)b << 12) + j0 + row) << 6) + col] = c;
                scb[col * CBS + row] = f2bf(c);
            }
    }
    __syncthreads();
    {   // condT writeback: [b*64+f2][j] coalesced, 32B/thread
        const int f2 = t >> 2, seg = t & 3;
        ushort_t* dst = condT + (((size_t)b * 64 + f2) << 12) + j0 + seg * 16;
        *(uint4*)dst = *(const uint4*)&scb[f2 * CBS + seg * 16];
        *(uint4*)(dst + 8) = *(const uint4*)&scb[f2 * CBS + seg * 16 + 8];
    }
}

// ---------------- K3: fused edges->GEMM + deg + colbits (unchanged from r3) --------------
__device__ __forceinline__ void stage_chunk(
    const int4 pa, int it, int kq, ushort_t* dstbuf, int soff, u64_t& regm, int& cnt)
{
    const u64_t b0 = __ballot(pa.x != 0);
    const u64_t b1 = __ballot(pa.y != 0);
    const u64_t b2 = __ballot(pa.z != 0);
    const u64_t b3 = __ballot(pa.w != 0);
    const uint_t m0 = (uint_t)(b0 | (b0 >> 32)), m1 = (uint_t)(b1 | (b1 >> 32));
    const uint_t m2 = (uint_t)(b2 | (b2 >> 32)), m3 = (uint_t)(b3 | (b3 >> 32));
    const uint_t nib = ((m0 >> kq) & 1u) | (((m1 >> kq) & 1u) << 1) |
                       (((m2 >> kq) & 1u) << 2) | (((m3 >> kq) & 1u) << 3);
    regm |= (u64_t)nib << (it * 4);
    cnt += (pa.x != 0) + (pa.y != 0) + (pa.z != 0) + (pa.w != 0);
    const uint_t h01 = (pa.x ? 0x3F80u : 0u) | (pa.y ? 0x3F800000u : 0u);
    const uint_t h23 = (pa.z ? 0x3F80u : 0u) | (pa.w ? 0x3F800000u : 0u);
    *(uint2*)(dstbuf + soff) = make_uint2(h01, h23);
}

__global__ __launch_bounds__(1024) void k3_gemm(
    const int* __restrict__ edges, const ushort_t* __restrict__ condT,
    float* __restrict__ agg0, float* __restrict__ agg1,
    int* __restrict__ degI, uint_t* __restrict__ colbits)
{
    const int t = threadIdx.x;
    const int stripe = blockIdx.x >> 1, kh = blockIdx.x & 1;
    const int j0 = stripe * 32, kb = kh * 2048;

    __shared__ __align__(16) ushort_t abuf[2][4096];
    __shared__ int degs[1024];
    __shared__ u64_t colsh[16][32];
    __shared__ u64_t colr[32];

    const int w = t >> 6, l = t & 63;
    const int r = t >> 5, kq = t & 31;
    const int rl = r & 15, rh = r >> 4;

    const int ks_s = kq >> 3, q_s = (kq >> 1) & 3;
    const int soff = (rh * 2048 + ks_s * 512 + (q_s * 16 + rl) * 8 + (kq & 1) * 4) ^ (q_s << 4);
    const int aoff = (l * 8) ^ ((l >> 4) << 4);

    const int* ep = edges + (size_t)(j0 + r) * NN + kb + kq * 4;
    const ushort_t* bp = condT + (size_t)(w * 16 + (l & 15)) * NN + kb + (l >> 4) * 8;

    u64_t regm = 0; int cnt = 0;
    int4 pa = *(const int4*)ep;
    stage_chunk(pa, 0, kq, &abuf[0][0], soff, regm, cnt);
    __syncthreads();

    f32x4 acc0 = {0.f, 0.f, 0.f, 0.f};
    f32x4 acc1 = {0.f, 0.f, 0.f, 0.f};

    for (int it = 0; it < 16; ++it) {
        if (it < 15) pa = *(const int4*)(ep + (it + 1) * 128);
        const ushort_t* ab = &abuf[it & 1][0];
        const ushort_t* bpi = bp + it * 128;
        #pragma unroll
        for (int ks = 0; ks < 4; ++ks) {
            const bf16x8 bfv = *(const bf16x8*)(bpi + ks * 32);
            const bf16x8 a0 = *(const bf16x8*)(ab + ks * 512 + aoff);
            const bf16x8 a1 = *(const bf16x8*)(ab + 2048 + ks * 512 + aoff);
            acc0 = __builtin_amdgcn_mfma_f32_16x16x32_bf16(a0, bfv, acc0, 0, 0, 0);
            acc1 = __builtin_amdgcn_mfma_f32_16x16x32_bf16(a1, bfv, acc1, 0, 0, 0);
        }
        if (it < 15) stage_chunk(pa, it + 1, kq, &abuf[(it + 1) & 1][0], soff, regm, cnt);
        __syncthreads();
    }

    {
        float* aggS = kh ? agg1 : agg0;
        const int col = w * 16 + (l & 15);
        float* dst = aggS + ((size_t)(col >> 6) * NN << 6) + (col & 63);
        #pragma unroll
        for (int i = 0; i < 4; ++i) {
            const int ja = j0 + (l >> 4) * 4 + i;
            dst[(size_t)ja << 6] = acc0[i];
            dst[(size_t)(ja + 16) << 6] = acc1[i];
        }
    }
    degs[t] = cnt;
    if (l < 32) colsh[w][kq] = regm;
    __syncthreads();
    if (t < 32) {
        u64_t v = 0;
        #pragma unroll
        for (int w2 = 0; w2 < 16; ++w2) v |= colsh[w2][t];
        colr[t] = v;
        int s = 0;
        #pragma unroll
        for (int s2 = 0; s2 < 32; ++s2) s += degs[t * 32 + s2];
        atomicAdd(&degI[j0 + t], s);
    }
    __syncthreads();
    if (t < 64) {
        uint_t word = 0;
        #pragma unroll
        for (int s = 0; s < 8; ++s) {
            const int g = (t & 3) * 8 + s;
            const uint_t nib = (uint_t)((colr[g] >> ((t >> 2) * 4)) & 15u);
            word |= nib << (s * 4);
        }
        atomicOr(&colbits[kh * 64 + t], word);
    }
}

// ---------------- K4: MLP epilogue on MFMA; 64 rows/block, grid (64,4) -------------------
#define WGS 88    // 64-wide bf16 stride (176B: 16-aligned, 2-way banks)
#define WDS 136   // 128-wide bf16 stride (272B: 16-aligned, 2-way banks)
#define HS  69    // H fp32 stride (69 mod 32 coprime-ish: conflict-free phase O)
__global__ __launch_bounds__(256) void k4_mlp(
    const float* __restrict__ ts, const int* __restrict__ edges,
    const float* __restrict__ condf,
    const float* __restrict__ agg0, const float* __restrict__ agg1,
    const int* __restrict__ degI, const uint_t* __restrict__ colbits,
    const float* __restrict__ Wg1, const float* __restrict__ bg,
    const float* __restrict__ Wd, const float* __restrict__ bd,
    const float* __restrict__ Wo, const float* __restrict__ bo,
    float* __restrict__ out)
{
    const int b = blockIdx.y;
    const int j0 = blockIdx.x * 64;
    const int t = threadIdx.x;

    __shared__ ushort_t sWg1T[64 * WGS];   // [gout][in]
    __shared__ ushort_t sWdT[64 * WDS];    // [hout][in]
    __shared__ ushort_t aggB[64 * WGS];    // [row][f]  bf16 aggN
    __shared__ ushort_t catB[64 * WDS];    // [row][0..63 cond | 64..127 G]
    __shared__ float sH[64 * HS];          // [row][hout]
    __shared__ float sWo[256];
    __shared__ float sbg[64], sbd[64], sbo[4], sAlive[64];

    for (int i = t; i < 4096; i += 256) {
        const int in = i >> 6, o = i & 63;
        sWg1T[o * WGS + in] = f2bf(Wg1[i]);
    }
    for (int i = t; i < 8192; i += 256) {
        const int in = i >> 6, o = i & 63;
        sWdT[o * WDS + in] = f2bf(Wd[i]);
    }
    if (t < 256) sWo[t] = Wo[t];
    if (t < 64) { sbg[t] = bg[t]; sbd[t] = bd[t]; }
    if (t < 4) sbo[t] = bo[t];
    if (t < 64) {
        const int j = j0 + t;
        sAlive[t] = (float)((colbits[j >> 5] >> (j & 31)) & 1u);
    }
    {   // phase 0: aggN = (agg0+agg1 - diag*bf16(cond))/deg -> bf16; cond -> bf16
        const int r = t >> 2, fs = t & 3;
        const int j = j0 + r;
        const float dv = (float)degI[j];
        const float inv = 1.f / (dv > 0.f ? dv : 1.f);
        const float dgf = edges[(size_t)j * NN + j] ? 1.f : 0.f;
        const size_t base = (((size_t)b << 12) + j) << 6;
        #pragma unroll
        for (int q = 0; q < 4; ++q) {
            const int f = fs * 16 + q * 4;
            const float4 a0 = *(const float4*)(agg0 + base + f);
            const float4 a1 = *(const float4*)(agg1 + base + f);
            const float4 c4 = *(const float4*)(condf + base + f);
            const float n0 = (a0.x + a1.x - dgf * bf16f(c4.x)) * inv;
            const float n1 = (a0.y + a1.y - dgf * bf16f(c4.y)) * inv;
            const float n2 = (a0.z + a1.z - dgf * bf16f(c4.z)) * inv;
            const float n3 = (a0.w + a1.w - dgf * bf16f(c4.w)) * inv;
            *(uint2*)&aggB[r * WGS + f] = make_uint2(pk2(n0, n1), pk2(n2, n3));
            *(uint2*)&catB[r * WDS + f] = make_uint2(pk2(c4.x, c4.y), pk2(c4.z, c4.w));
        }
    }
    __syncthreads();

    const int w = t >> 6, l = t & 63;
    const int m0 = w * 16, kseg = (l >> 4) * 8;

    {   // phase G: G = tanh(aggN @ Wg1 + bg) * alive -> catB[.][64..127]
        f32x4 acc[4] = {};
        #pragma unroll
        for (int ks = 0; ks < 2; ++ks) {
            const bf16x8 av = *(const bf16x8*)&aggB[(m0 + (l & 15)) * WGS + ks * 32 + kseg];
            #pragma unroll
            for (int ct = 0; ct < 4; ++ct) {
                const bf16x8 bv = *(const bf16x8*)&sWg1T[(ct * 16 + (l & 15)) * WGS + ks * 32 + kseg];
                acc[ct] = __builtin_amdgcn_mfma_f32_16x16x32_bf16(av, bv, acc[ct], 0, 0, 0);
            }
        }
        #pragma unroll
        for (int ct = 0; ct < 4; ++ct)
            #pragma unroll
            for (int i = 0; i < 4; ++i) {
                const int row = m0 + (l >> 4) * 4 + i;
                const int col = ct * 16 + (l & 15);
                const float g = tanh_fast(acc[ct][i] + sbg[col]) * sAlive[row];
                catB[row * WDS + 64 + col] = f2bf(g);
            }
    }
    __syncthreads();
    {   // phase H: h = relu(cat @ Wd + bd) -> sH
        f32x4 acc[4] = {};
        #pragma unroll
        for (int ks = 0; ks < 4; ++ks) {
            const bf16x8 av = *(const bf16x8*)&catB[(m0 + (l & 15)) * WDS + ks * 32 + kseg];
            #pragma unroll
            for (int ct = 0; ct < 4; ++ct) {
                const bf16x8 bv = *(const bf16x8*)&sWdT[(ct * 16 + (l & 15)) * WDS + ks * 32 + kseg];
                acc[ct] = __builtin_amdgcn_mfma_f32_16x16x32_bf16(av, bv, acc[ct], 0, 0, 0);
            }
        }
        #pragma unroll
        for (int ct = 0; ct < 4; ++ct)
            #pragma unroll
            for (int i = 0; i < 4; ++i) {
                const int row = m0 + (l >> 4) * 4 + i;
                const int col = ct * 16 + (l & 15);
                sH[row * HS + col] = fmaxf(acc[ct][i] + sbd[col], 0.f);
            }
    }
    __syncthreads();
    {   // phase O: out = seg_last + tanh(h @ Wo + bo); one (row,d) per thread
        const int r = t >> 2, d = t & 3;
        const int j = j0 + r;
        float s = sbo[d];
        #pragma unroll 8
        for (int f = 0; f < 64; ++f) s += sH[r * HS + f] * sWo[f * 4 + d];
        const float segl = ts[((((size_t)b * TT + 4) << 12) + j) * 4 + d];
        out[((((size_t)b << 12) + j) << 2) + d] = segl + tanh_fast(s);
    }
}

// ---------------- launcher ----------------------------------------------------------------
extern "C" void kernel_launch(void* const* d_in, const int* in_sizes, int n_in,
                              void* d_out, int out_size, void* d_ws, size_t ws_size,
                              hipStream_t stream)
{
    (void)in_sizes; (void)n_in; (void)out_size; (void)ws_size;
    const float* ts    = (const float*)d_in[0];
    const int*   edges = (const int*)d_in[1];
    const float* Wc1   = (const float*)d_in[2];
    const float* bc1   = (const float*)d_in[3];
    const float* Wc2   = (const float*)d_in[4];
    const float* bc2   = (const float*)d_in[5];
    const float* Wg1   = (const float*)d_in[6];
    const float* bg    = (const float*)d_in[7];
    const float* Wd    = (const float*)d_in[8];
    const float* bd    = (const float*)d_in[9];
    const float* Wo    = (const float*)d_in[10];
    const float* bo    = (const float*)d_in[11];
    float* out = (float*)d_out;

    char* ws = (char*)d_ws;
    ushort_t* condT   = (ushort_t*)(ws);                        // 2 MiB
    float*    condf   = (float*)(ws + (size_t)(2 << 20));       // 4 MiB
    float*    agg0    = (float*)(ws + (size_t)(6 << 20));       // 4 MiB
    float*    agg1    = (float*)(ws + (size_t)(10 << 20));      // 4 MiB
    int*      degI    = (int*)(ws + (size_t)(14 << 20));        // 16 KiB
    uint_t*   colbits = (uint_t*)(ws + (size_t)(14 << 20) + 16384); // 512 B

    hipMemsetAsync(degI, 0, 16384 + 512, stream);

    k1_cond<<<dim3(64, 4), 256, 0, stream>>>(ts, Wc1, bc1, Wc2, bc2, condf, condT);
    k3_gemm<<<256, 1024, 0, stream>>>(edges, condT, agg0, agg1, degI, colbits);
    k4_mlp<<<dim3(64, 4), 256, 0, stream>>>(ts, edges, condf, agg0, agg1, degI, colbits,
                                            Wg1, bg, Wd, bd, Wo, bo, out);
}

// Round 5
// 164.662 us; speedup vs baseline: 1.6583x; 1.0054x over previous
//
#include <hip/hip_runtime.h>
#include <math.h>

typedef unsigned short ushort_t;
typedef unsigned int uint_t;
typedef unsigned long long u64_t;
typedef __attribute__((ext_vector_type(8))) __bf16 bf16x8;
typedef __attribute__((ext_vector_type(4))) float f32x4;

#define NN 4096
#define TT 5
#define F1 32
#define F2 64

// round-to-nearest-even fp32 -> bf16 bits
__device__ __forceinline__ ushort_t f2bf(float x) {
    union { float f; uint_t u; } v; v.f = x;
    uint_t r = (v.u + 0x7FFFu + ((v.u >> 16) & 1u)) >> 16;
    return (ushort_t)r;
}
__device__ __forceinline__ float bf16f(float x) {
    union { float f; uint_t u; } v; v.f = x;
    v.u = (v.u + 0x7FFFu + ((v.u >> 16) & 1u)) & 0xFFFF0000u;
    return v.f;
}
__device__ __forceinline__ uint_t pk2(float a, float b) {
    return (uint_t)f2bf(a) | ((uint_t)f2bf(b) << 16);
}
// fast tanh: (e^2x - 1)/(e^2x + 1), clamped; err ~1e-6 (irrelevant vs bf16 noise)
__device__ __forceinline__ float tanh_fast(float x) {
    const float xc = fminf(fmaxf(x, -10.f), 10.f);
    const float e = __expf(2.f * xc);
    return (e - 1.f) * __builtin_amdgcn_rcpf(e + 1.f);
}

// ---------------- K1: conv1 (VALU) + conv2 (MFMA) -> condf fp32 + condT bf16 -------------
#define H1S 104
#define CBS 80
__global__ __launch_bounds__(256) void k1_cond(
    const float* __restrict__ ts, const float* __restrict__ Wc1, const float* __restrict__ bc1,
    const float* __restrict__ Wc2, const float* __restrict__ bc2,
    float* __restrict__ condf, ushort_t* __restrict__ condT)
{
    const int b = blockIdx.y;
    const int j0 = blockIdx.x * 64;
    const int t = threadIdx.x;

    __shared__ float sWc1[384];
    __shared__ float sbc1[F1];
    __shared__ float sbc2[F2];
    __shared__ ushort_t sWc2T[64 * H1S];
    __shared__ ushort_t h1B[64 * H1S];
    __shared__ ushort_t scb[64 * CBS];

    for (int i = t; i < 384; i += 256) sWc1[i] = Wc1[i];
    if (t < F1) sbc1[t] = bc1[t];
    if (t < F2) sbc2[t] = bc2[t];
    for (int i = t; i < 96 * 64; i += 256) {
        const int e = i >> 6, f = i & 63;
        sWc2T[f * H1S + e] = f2bf(Wc2[i]);
    }
    __syncthreads();

    {   // phase A: h1 = relu(conv1)
        const int n = t & 63, f10 = (t >> 6) * 8;
        const int j = j0 + n;
        float4 x[5];
        #pragma unroll
        for (int tt = 0; tt < 5; ++tt)
            x[tt] = *(const float4*)(ts + ((((size_t)b * TT + tt) << 12) + j) * 4);
        #pragma unroll
        for (int tt0 = 0; tt0 < 3; ++tt0) {
            #pragma unroll
            for (int ff = 0; ff < 8; ++ff) {
                const int f1 = f10 + ff;
                float a = sbc1[f1];
                #pragma unroll
                for (int dt = 0; dt < 3; ++dt) {
                    const float4 xx = x[tt0 + dt];
                    a += xx.x * sWc1[(dt * 4 + 0) * F1 + f1];
                    a += xx.y * sWc1[(dt * 4 + 1) * F1 + f1];
                    a += xx.z * sWc1[(dt * 4 + 2) * F1 + f1];
                    a += xx.w * sWc1[(dt * 4 + 3) * F1 + f1];
                }
                h1B[n * H1S + tt0 * 32 + f1] = f2bf(fmaxf(a, 0.f));
            }
        }
    }
    __syncthreads();

    {   // phase B: cond = h1 @ Wc2 + bc2 via MFMA
        const int w = t >> 6, l = t & 63;
        const int m0 = w * 16, kseg = (l >> 4) * 8;
        f32x4 acc[4] = {};
        #pragma unroll
        for (int ks = 0; ks < 3; ++ks) {
            const bf16x8 av = *(const bf16x8*)&h1B[(m0 + (l & 15)) * H1S + ks * 32 + kseg];
            #pragma unroll
            for (int ct = 0; ct < 4; ++ct) {
                const bf16x8 bv = *(const bf16x8*)&sWc2T[(ct * 16 + (l & 15)) * H1S + ks * 32 + kseg];
                acc[ct] = __builtin_amdgcn_mfma_f32_16x16x32_bf16(av, bv, acc[ct], 0, 0, 0);
            }
        }
        #pragma unroll
        for (int ct = 0; ct < 4; ++ct)
            #pragma unroll
            for (int i = 0; i < 4; ++i) {
                const int row = m0 + (l >> 4) * 4 + i;
                const int col = ct * 16 + (l & 15);
                const float c = acc[ct][i] + sbc2[col];
                condf[((((size_t)b << 12) + j0 + row) << 6) + col] = c;
                scb[col * CBS + row] = f2bf(c);
            }
    }
    __syncthreads();
    {   // condT writeback
        const int f2 = t >> 2, seg = t & 3;
        ushort_t* dst = condT + (((size_t)b * 64 + f2) << 12) + j0 + seg * 16;
        *(uint4*)dst = *(const uint4*)&scb[f2 * CBS + seg * 16];
        *(uint4*)(dst + 8) = *(const uint4*)&scb[f2 * CBS + seg * 16 + 8];
    }
}

// ---------------- K3: barrier-light edges GEMM + deg + colbits ---------------------------
// grid 512 = 128 row-stripes(32r) x 4 k-splits(1024); 1024 thr (16 waves), 2 blocks/CU.
// Whole A-tile (32r x 1024k) expanded to bf16 in 64KB LDS in two 4-chunk groups;
// K-loop itself is barrier-free: ds_read A + direct global b128 B (L2-resident condT).
__device__ __forceinline__ void stage_chunk(
    const int4 pa, int it, int kq, ushort_t* dstbuf, int soff, uint_t& regm, int& cnt)
{
    const u64_t b0 = __ballot(pa.x != 0);
    const u64_t b1 = __ballot(pa.y != 0);
    const u64_t b2 = __ballot(pa.z != 0);
    const u64_t b3 = __ballot(pa.w != 0);
    const uint_t m0 = (uint_t)(b0 | (b0 >> 32)), m1 = (uint_t)(b1 | (b1 >> 32));
    const uint_t m2 = (uint_t)(b2 | (b2 >> 32)), m3 = (uint_t)(b3 | (b3 >> 32));
    const uint_t nib = ((m0 >> kq) & 1u) | (((m1 >> kq) & 1u) << 1) |
                       (((m2 >> kq) & 1u) << 2) | (((m3 >> kq) & 1u) << 3);
    regm |= nib << (it * 4);
    cnt += (pa.x != 0) + (pa.y != 0) + (pa.z != 0) + (pa.w != 0);
    const uint_t h01 = (pa.x ? 0x3F80u : 0u) | (pa.y ? 0x3F800000u : 0u);
    const uint_t h23 = (pa.z ? 0x3F80u : 0u) | (pa.w ? 0x3F800000u : 0u);
    *(uint2*)(dstbuf + soff) = make_uint2(h01, h23);
}

__global__ __launch_bounds__(1024, 8) void k3_gemm(
    const int* __restrict__ edges, const ushort_t* __restrict__ condT,
    float* __restrict__ agg0, float* __restrict__ agg1,
    float* __restrict__ agg2, float* __restrict__ agg3,
    int* __restrict__ degI, uint_t* __restrict__ colbits)
{
    const int t = threadIdx.x;
    const int stripe = blockIdx.x >> 2, ks4 = blockIdx.x & 3;
    const int j0 = stripe * 32, kb = ks4 * 1024;

    __shared__ __align__(16) ushort_t abuf[8][4096];   // 64 KB: 8 chunks x (32r x 128k)

    const int w = t >> 6, l = t & 63;
    const int r = t >> 5, kq = t & 31;
    const int rl = r & 15, rh = r >> 4;
    const int ks_s = kq >> 3, q_s = (kq >> 1) & 3;
    const int soff = (rh * 2048 + ks_s * 512 + (q_s * 16 + rl) * 8 + (kq & 1) * 4) ^ (q_s << 4);
    const int aoff = (l * 8) ^ ((l >> 4) << 4);

    const int* ep = edges + (size_t)(j0 + r) * NN + kb + kq * 4;
    const ushort_t* bp = condT + (size_t)(w * 16 + (l & 15)) * NN + kb + (l >> 4) * 8;

    uint_t regm = 0; int cnt = 0;
    int4 pa[4];

    // stage group 0 (chunks 0..3) — all 4 loads in flight together
    #pragma unroll
    for (int c = 0; c < 4; ++c) pa[c] = *(const int4*)(ep + c * 128);
    #pragma unroll
    for (int c = 0; c < 4; ++c) stage_chunk(pa[c], c, kq, &abuf[c][0], soff, regm, cnt);
    __syncthreads();

    // issue group-1 loads now; they fly during compute of group 0
    #pragma unroll
    for (int c = 0; c < 4; ++c) pa[c] = *(const int4*)(ep + (c + 4) * 128);

    f32x4 acc0 = {0.f, 0.f, 0.f, 0.f};
    f32x4 acc1 = {0.f, 0.f, 0.f, 0.f};

    #pragma unroll
    for (int ch = 0; ch < 4; ++ch) {
        const ushort_t* ab = &abuf[ch][0];
        const ushort_t* bpi = bp + ch * 128;
        #pragma unroll
        for (int ks = 0; ks < 4; ++ks) {
            const bf16x8 bfv = *(const bf16x8*)(bpi + ks * 32);
            const bf16x8 a0 = *(const bf16x8*)(ab + ks * 512 + aoff);
            const bf16x8 a1 = *(const bf16x8*)(ab + 2048 + ks * 512 + aoff);
            acc0 = __builtin_amdgcn_mfma_f32_16x16x32_bf16(a0, bfv, acc0, 0, 0, 0);
            acc1 = __builtin_amdgcn_mfma_f32_16x16x32_bf16(a1, bfv, acc1, 0, 0, 0);
        }
    }
    // stage group 1 (chunks 4..7) — writes regions no one reads yet
    #pragma unroll
    for (int c = 0; c < 4; ++c) stage_chunk(pa[c], c + 4, kq, &abuf[c + 4][0], soff, regm, cnt);
    __syncthreads();

    #pragma unroll
    for (int ch = 4; ch < 8; ++ch) {
        const ushort_t* ab = &abuf[ch][0];
        const ushort_t* bpi = bp + ch * 128;
        #pragma unroll
        for (int ks = 0; ks < 4; ++ks) {
            const bf16x8 bfv = *(const bf16x8*)(bpi + ks * 32);
            const bf16x8 a0 = *(const bf16x8*)(ab + ks * 512 + aoff);
            const bf16x8 a1 = *(const bf16x8*)(ab + 2048 + ks * 512 + aoff);
            acc0 = __builtin_amdgcn_mfma_f32_16x16x32_bf16(a0, bfv, acc0, 0, 0, 0);
            acc1 = __builtin_amdgcn_mfma_f32_16x16x32_bf16(a1, bfv, acc1, 0, 0, 0);
        }
    }

    // epilogue: plain stores to this split's slab
    {
        float* aggS = (ks4 == 0) ? agg0 : (ks4 == 1) ? agg1 : (ks4 == 2) ? agg2 : agg3;
        const int col = w * 16 + (l & 15);
        float* dst = aggS + ((size_t)(col >> 6) * NN << 6) + (col & 63);
        #pragma unroll
        for (int i = 0; i < 4; ++i) {
            const int ja = j0 + (l >> 4) * 4 + i;
            dst[(size_t)ja << 6] = acc0[i];
            dst[(size_t)(ja + 16) << 6] = acc1[i];
        }
    }
    // deg: shfl-reduce over the 32 lanes of each row (lanes 0-31 / 32-63 separately)
    {
        int s = cnt;
        #pragma unroll
        for (int off = 16; off >= 1; off >>= 1) s += __shfl_down(s, off, 32);
        if (kq == 0) atomicAdd(&degI[j0 + r], s);
    }
    // colbits: overlay reduction scratch on abuf (compute done)
    __syncthreads();
    uint_t* colsh = (uint_t*)&abuf[0][0];   // [0..511]: per-wave masks; [512..543]: colr
    if (l < 32) colsh[w * 32 + kq] = regm;
    __syncthreads();
    if (t < 32) {
        uint_t v = 0;
        #pragma unroll
        for (int w2 = 0; w2 < 16; ++w2) v |= colsh[w2 * 32 + t];
        colsh[512 + t] = v;
    }
    __syncthreads();
    if (t < 32) {
        const int it = t >> 2, koct = t & 3;
        uint_t word = 0;
        #pragma unroll
        for (int s2 = 0; s2 < 8; ++s2)
            word |= ((colsh[512 + koct * 8 + s2] >> (it * 4)) & 15u) << (s2 * 4);
        atomicOr(&colbits[(kb >> 5) + t], word);
    }
}

// ---------------- K4: MLP epilogue on MFMA; 64 rows/block, grid (64,4) -------------------
#define WGS 88
#define WDS 136
#define HS  69
__global__ __launch_bounds__(256) void k4_mlp(
    const float* __restrict__ ts, const int* __restrict__ edges,
    const float* __restrict__ condf,
    const float* __restrict__ agg0, const float* __restrict__ agg1,
    const float* __restrict__ agg2, const float* __restrict__ agg3,
    const int* __restrict__ degI, const uint_t* __restrict__ colbits,
    const float* __restrict__ Wg1, const float* __restrict__ bg,
    const float* __restrict__ Wd, const float* __restrict__ bd,
    const float* __restrict__ Wo, const float* __restrict__ bo,
    float* __restrict__ out)
{
    const int b = blockIdx.y;
    const int j0 = blockIdx.x * 64;
    const int t = threadIdx.x;

    __shared__ ushort_t sWg1T[64 * WGS];
    __shared__ ushort_t sWdT[64 * WDS];
    __shared__ ushort_t aggB[64 * WGS];
    __shared__ ushort_t catB[64 * WDS];
    __shared__ float sH[64 * HS];
    __shared__ float sWo[256];
    __shared__ float sbg[64], sbd[64], sbo[4], sAlive[64];

    for (int i = t; i < 4096; i += 256) {
        const int in = i >> 6, o = i & 63;
        sWg1T[o * WGS + in] = f2bf(Wg1[i]);
    }
    for (int i = t; i < 8192; i += 256) {
        const int in = i >> 6, o = i & 63;
        sWdT[o * WDS + in] = f2bf(Wd[i]);
    }
    if (t < 256) sWo[t] = Wo[t];
    if (t < 64) { sbg[t] = bg[t]; sbd[t] = bd[t]; }
    if (t < 4) sbo[t] = bo[t];
    if (t < 64) {
        const int j = j0 + t;
        sAlive[t] = (float)((colbits[j >> 5] >> (j & 31)) & 1u);
    }
    {   // phase 0: aggN = (sum slabs - diag*bf16(cond))/deg -> bf16; cond -> bf16
        const int r = t >> 2, fs = t & 3;
        const int j = j0 + r;
        const float dv = (float)degI[j];
        const float inv = 1.f / (dv > 0.f ? dv : 1.f);
        const float dgf = edges[(size_t)j * NN + j] ? 1.f : 0.f;
        const size_t base = (((size_t)b << 12) + j) << 6;
        #pragma unroll
        for (int q = 0; q < 4; ++q) {
            const int f = fs * 16 + q * 4;
            const float4 a0 = *(const float4*)(agg0 + base + f);
            const float4 a1 = *(const float4*)(agg1 + base + f);
            const float4 a2 = *(const float4*)(agg2 + base + f);
            const float4 a3 = *(const float4*)(agg3 + base + f);
            const float4 c4 = *(const float4*)(condf + base + f);
            const float n0 = (a0.x + a1.x + a2.x + a3.x - dgf * bf16f(c4.x)) * inv;
            const float n1 = (a0.y + a1.y + a2.y + a3.y - dgf * bf16f(c4.y)) * inv;
            const float n2 = (a0.z + a1.z + a2.z + a3.z - dgf * bf16f(c4.z)) * inv;
            const float n3 = (a0.w + a1.w + a2.w + a3.w - dgf * bf16f(c4.w)) * inv;
            *(uint2*)&aggB[r * WGS + f] = make_uint2(pk2(n0, n1), pk2(n2, n3));
            *(uint2*)&catB[r * WDS + f] = make_uint2(pk2(c4.x, c4.y), pk2(c4.z, c4.w));
        }
    }
    __syncthreads();

    const int w = t >> 6, l = t & 63;
    const int m0 = w * 16, kseg = (l >> 4) * 8;

    {   // phase G
        f32x4 acc[4] = {};
        #pragma unroll
        for (int ks = 0; ks < 2; ++ks) {
            const bf16x8 av = *(const bf16x8*)&aggB[(m0 + (l & 15)) * WGS + ks * 32 + kseg];
            #pragma unroll
            for (int ct = 0; ct < 4; ++ct) {
                const bf16x8 bv = *(const bf16x8*)&sWg1T[(ct * 16 + (l & 15)) * WGS + ks * 32 + kseg];
                acc[ct] = __builtin_amdgcn_mfma_f32_16x16x32_bf16(av, bv, acc[ct], 0, 0, 0);
            }
        }
        #pragma unroll
        for (int ct = 0; ct < 4; ++ct)
            #pragma unroll
            for (int i = 0; i < 4; ++i) {
                const int row = m0 + (l >> 4) * 4 + i;
                const int col = ct * 16 + (l & 15);
                const float g = tanh_fast(acc[ct][i] + sbg[col]) * sAlive[row];
                catB[row * WDS + 64 + col] = f2bf(g);
            }
    }
    __syncthreads();
    {   // phase H
        f32x4 acc[4] = {};
        #pragma unroll
        for (int ks = 0; ks < 4; ++ks) {
            const bf16x8 av = *(const bf16x8*)&catB[(m0 + (l & 15)) * WDS + ks * 32 + kseg];
            #pragma unroll
            for (int ct = 0; ct < 4; ++ct) {
                const bf16x8 bv = *(const bf16x8*)&sWdT[(ct * 16 + (l & 15)) * WDS + ks * 32 + kseg];
                acc[ct] = __builtin_amdgcn_mfma_f32_16x16x32_bf16(av, bv, acc[ct], 0, 0, 0);
            }
        }
        #pragma unroll
        for (int ct = 0; ct < 4; ++ct)
            #pragma unroll
            for (int i = 0; i < 4; ++i) {
                const int row = m0 + (l >> 4) * 4 + i;
                const int col = ct * 16 + (l & 15);
                sH[row * HS + col] = fmaxf(acc[ct][i] + sbd[col], 0.f);
            }
    }
    __syncthreads();
    {   // phase O
        const int r = t >> 2, d = t & 3;
        const int j = j0 + r;
        float s = sbo[d];
        #pragma unroll 8
        for (int f = 0; f < 64; ++f) s += sH[r * HS + f] * sWo[f * 4 + d];
        const float segl = ts[((((size_t)b * TT + 4) << 12) + j) * 4 + d];
        out[((((size_t)b << 12) + j) << 2) + d] = segl + tanh_fast(s);
    }
}

// ---------------- launcher ----------------------------------------------------------------
extern "C" void kernel_launch(void* const* d_in, const int* in_sizes, int n_in,
                              void* d_out, int out_size, void* d_ws, size_t ws_size,
                              hipStream_t stream)
{
    (void)in_sizes; (void)n_in; (void)out_size; (void)ws_size;
    const float* ts    = (const float*)d_in[0];
    const int*   edges = (const int*)d_in[1];
    const float* Wc1   = (const float*)d_in[2];
    const float* bc1   = (const float*)d_in[3];
    const float* Wc2   = (const float*)d_in[4];
    const float* bc2   = (const float*)d_in[5];
    const float* Wg1   = (const float*)d_in[6];
    const float* bg    = (const float*)d_in[7];
    const float* Wd    = (const float*)d_in[8];
    const float* bd    = (const float*)d_in[9];
    const float* Wo    = (const float*)d_in[10];
    const float* bo    = (const float*)d_in[11];
    float* out = (float*)d_out;

    char* ws = (char*)d_ws;
    ushort_t* condT   = (ushort_t*)(ws);                        // 2 MiB
    float*    condf   = (float*)(ws + (size_t)(2 << 20));       // 4 MiB
    float*    agg0    = (float*)(ws + (size_t)(6 << 20));       // 4 MiB
    float*    agg1    = (float*)(ws + (size_t)(10 << 20));      // 4 MiB
    float*    agg2    = (float*)(ws + (size_t)(14 << 20));      // 4 MiB
    float*    agg3    = (float*)(ws + (size_t)(18 << 20));      // 4 MiB
    int*      degI    = (int*)(ws + (size_t)(22 << 20));        // 16 KiB
    uint_t*   colbits = (uint_t*)(ws + (size_t)(22 << 20) + 16384); // 512 B

    hipMemsetAsync(degI, 0, 16384 + 512, stream);

    k1_cond<<<dim3(64, 4), 256, 0, stream>>>(ts, Wc1, bc1, Wc2, bc2, condf, condT);
    k3_gemm<<<512, 1024, 0, stream>>>(edges, condT, agg0, agg1, agg2, agg3, degI, colbits);
    k4_mlp<<<dim3(64, 4), 256, 0, stream>>>(ts, edges, condf, agg0, agg1, agg2, agg3,
                                            degI, colbits, Wg1, bg, Wd, bd, Wo, bo, out);
}